// Round 2
// baseline (571.933 us; speedup 1.0000x reference)
//
#include <hip/hip_runtime.h>

typedef __bf16 bf16;
typedef __attribute__((ext_vector_type(8))) __bf16 bf16x8;
typedef __attribute__((ext_vector_type(4))) __bf16 bf16x4;
typedef __attribute__((ext_vector_type(4))) float f32x4;

#define B_  32
#define S_  2048
#define DC  1024
#define DQ  1024
#define H_  512
#define NCH 16             // s-chunks for expected_ctx (compacted: 16 x 128 covers 2048)
#define NBLK 16            // row-blocks per batch in k_gemm (16 x 128 = 2048 worst case)

// async global->LDS, 16B per lane
#define GLD16(g, l) __builtin_amdgcn_global_load_lds( \
    (__attribute__((address_space(1))) void*)(g),     \
    (__attribute__((address_space(3))) void*)(l), 16, 0, 0)

// ---------- Prep ----------
// blocks 0..255   : Wc -> bf16 transpose tiles  WcT2 [kb(32)][h(512)][kk(32)]
// blocks 256..511 : qb[b][h] = query[b] . Wq[:,h] + b1[h]
// blocks 512..543 : per-batch compaction of mask==1 row indices (global row ids)
__global__ __launch_bounds__(256) void k_prep(const float* __restrict__ W1,
                                              const float* __restrict__ query,
                                              const float* __restrict__ b1,
                                              const int*   __restrict__ mask,
                                              bf16* __restrict__ WcT2,
                                              float* __restrict__ qb,
                                              int* __restrict__ glist,
                                              int* __restrict__ cnts) {
    const int bid = blockIdx.x, tid = threadIdx.x;
    if (bid < 256) {
        // W1[:1024] (k-major) -> WcT2 [kb][h][kk] bf16 (plain layout)
        __shared__ bf16 t[32 * 68];            // [kk][h-in-tile], pad 4
        const int kb = bid >> 3;               // 0..31
        const int cb = bid & 7;                // 0..7, 64-col tile
        #pragma unroll
        for (int i = 0; i < 2; ++i) {
            int idx = i * 256 + tid;           // 0..511
            int k  = idx >> 4;                 // 0..31
            int h4 = (idx & 15) * 4;           // 0..60
            const float4 v = *(const float4*)(W1 + ((size_t)(kb * 32 + k)) * H_ + cb * 64 + h4);
            bf16x4 pk = { (bf16)v.x, (bf16)v.y, (bf16)v.z, (bf16)v.w };
            *(bf16x4*)(&t[k * 68 + h4]) = pk;
        }
        __syncthreads();
        const int col = tid >> 2;              // 0..63
        const int kk0 = (tid & 3) * 8;         // 0,8,16,24
        bf16x8 o;
        #pragma unroll
        for (int j = 0; j < 8; ++j) o[j] = t[(kk0 + j) * 68 + col];
        *(bf16x8*)(WcT2 + (size_t)kb * 16384 + (size_t)(cb * 64 + col) * 32 + kk0) = o;
    } else if (bid < 512) {
        // qb GEMV
        const int r = bid - 256;
        const int hblk = r & 7;                // 0..7
        const int b    = r >> 3;               // 0..31
        __shared__ float q[DQ];
        __shared__ float red[256];
        #pragma unroll
        for (int i = 0; i < 4; ++i)
            q[tid + i * 256] = query[(size_t)b * DQ + tid + i * 256];
        __syncthreads();
        const int h  = hblk * 64 + (tid & 63);
        const int kc = tid >> 6;               // 0..3
        const float* w = W1 + (size_t)DC * H_ + (size_t)(kc * 256) * H_ + h;
        const float* qv = q + kc * 256;
        float acc = 0.0f;
        #pragma unroll 8
        for (int k = 0; k < 256; ++k)
            acc = fmaf(qv[k], w[(size_t)k * H_], acc);
        red[tid] = acc;
        __syncthreads();
        if (tid < 64)
            qb[(size_t)b * H_ + hblk * 64 + tid] =
                red[tid] + red[tid + 64] + red[tid + 128] + red[tid + 192] + b1[hblk * 64 + tid];
    } else {
        // compaction: list of global row ids (b*2048+s) where mask==1, padded with b*2048
        const int b = bid - 512;
        __shared__ int sc[256];
        int c = 0;
        #pragma unroll
        for (int i = 0; i < 8; ++i)
            if (mask[(size_t)b * S_ + tid * 8 + i] != 0) ++c;
        sc[tid] = c;
        __syncthreads();
        for (int o = 1; o < 256; o <<= 1) {
            int v = sc[tid];
            int u = (tid >= o) ? sc[tid - o] : 0;
            __syncthreads();
            sc[tid] = v + u;
            __syncthreads();
        }
        const int total = sc[255];
        int w = sc[tid] - c;                   // exclusive offset
        for (int i = 0; i < 8; ++i) {
            int s = tid * 8 + i;
            if (mask[(size_t)b * S_ + s] != 0)
                glist[(size_t)b * S_ + (w++)] = b * S_ + s;
        }
        for (int pos = total + tid; pos < S_; pos += 256)
            glist[(size_t)b * S_ + pos] = b * S_;
        if (tid == 0) cnts[b] = total;
    }
}

// ---------- Kernel G: score[row] = sum_h tanh(ctx@Wc + qb)[h]*w2[h], unmasked rows only ----
// grid 512 (16 blocks/batch, inactive blocks exit). 512 thr = 8 waves (2m x 4n),
// wave tile 64x128 over a 128-row compacted gather.
// A: global->VGPR direct (no LDS), software-pipelined one step ahead.
// B: LDS triple-buffered via global_load_lds, counted vmcnt(12), raw s_barrier.
__global__ __launch_bounds__(512, 2) void k_gemm(const float* __restrict__ ctx,
                                                 const bf16*  __restrict__ WcT2,
                                                 const float* __restrict__ qb,
                                                 const float* __restrict__ W2,
                                                 const int*   __restrict__ glist,
                                                 const int*   __restrict__ cnts,
                                                 float* __restrict__ score) {
    __shared__ char smem[98304 + 2048];        // Bh 3x32KB, red 2KB (disjoint)
    bf16*  Bh  = (bf16*)smem;
    float* red = (float*)(smem + 98304);

    const int tid = threadIdx.x;
    const int b   = blockIdx.x >> 4;
    const int blk = blockIdx.x & (NBLK - 1);
    const int cnt = cnts[b];
    if (blk * 128 >= cnt) return;

    const int lane = tid & 63;
    const int wv   = tid >> 6;
    const int wm   = wv & 1;
    const int wn   = wv >> 1;
    const int l16  = lane & 15;
    const int quad = lane >> 4;

    // per-lane compacted row ids for the 4 m-fragments
    const int* lrow = glist + (size_t)b * S_ + blk * 128 + wm * 64 + l16;
    const float* ap[4];
    #pragma unroll
    for (int mf = 0; mf < 4; ++mf)
        ap[mf] = ctx + (size_t)lrow[mf * 16] * DC + quad * 8;

    const bf16* bsrc = WcT2 + tid * 8;
    const int   boff = tid * 8;
    const int   b0   = (wn * 128 + l16) * 32 + quad * 8;

    f32x4 acc[4][8] = {};
    float4 alo[4], ahi[4];

    // ---- prologue: A(0) into regs; B(0), B(1) into LDS ----
    #pragma unroll
    for (int mf = 0; mf < 4; ++mf) {
        alo[mf] = *(const float4*)(ap[mf]);
        ahi[mf] = *(const float4*)(ap[mf] + 4);
    }
    #pragma unroll
    for (int i = 0; i < 4; ++i) GLD16(bsrc + i * 4096, Bh + boff + i * 4096);
    #pragma unroll
    for (int i = 0; i < 4; ++i) GLD16(bsrc + 16384 + i * 4096, Bh + 16384 + boff + i * 4096);
    asm volatile("s_waitcnt vmcnt(4)" ::: "memory");   // A(0)+B(0) done; B(1) in flight
    __builtin_amdgcn_s_barrier();
    __builtin_amdgcn_sched_barrier(0);

// one k-step: cvt A(KB) (compiler-waited), prefetch A(KB+1) regs + B(KB+2) LDS,
// read B(KB) frags, MFMA. Ledger: 12 VMEM issued/step; at barrier wait vmcnt(12)
// -> B(KB+1) (older than all 12) is done, A(KB+1)+B(KB+2) stay in flight.
#define KSTEP(KB, RD, WR)                                                      \
  {                                                                            \
    bf16x8 aF[4];                                                              \
    _Pragma("unroll")                                                          \
    for (int mf = 0; mf < 4; ++mf) {                                           \
      bf16x8 t;                                                                \
      t[0]=(bf16)alo[mf].x; t[1]=(bf16)alo[mf].y;                              \
      t[2]=(bf16)alo[mf].z; t[3]=(bf16)alo[mf].w;                              \
      t[4]=(bf16)ahi[mf].x; t[5]=(bf16)ahi[mf].y;                              \
      t[6]=(bf16)ahi[mf].z; t[7]=(bf16)ahi[mf].w;                              \
      aF[mf] = t;                                                              \
    }                                                                          \
    if ((KB) < 31) {                                                           \
      _Pragma("unroll")                                                        \
      for (int mf = 0; mf < 4; ++mf) {                                         \
        alo[mf] = *(const float4*)(ap[mf] + ((KB) + 1) * 32);                  \
        ahi[mf] = *(const float4*)(ap[mf] + ((KB) + 1) * 32 + 4);              \
      }                                                                        \
    }                                                                          \
    if ((KB) < 30) {                                                           \
      _Pragma("unroll")                                                        \
      for (int i = 0; i < 4; ++i)                                              \
        GLD16(bsrc + (size_t)((KB) + 2) * 16384 + i * 4096,                    \
              Bh + (WR) * 16384 + boff + i * 4096);                            \
    }                                                                          \
    bf16x8 bF[8];                                                              \
    _Pragma("unroll")                                                          \
    for (int nf = 0; nf < 8; ++nf)                                             \
      bF[nf] = *(const bf16x8*)(Bh + (RD) * 16384 + b0 + nf * 512);            \
    __builtin_amdgcn_s_setprio(1);                                             \
    _Pragma("unroll")                                                          \
    for (int mf = 0; mf < 4; ++mf)                                             \
      _Pragma("unroll")                                                        \
      for (int nf = 0; nf < 8; ++nf)                                           \
        acc[mf][nf] = __builtin_amdgcn_mfma_f32_16x16x32_bf16(aF[mf], bF[nf],  \
                                                              acc[mf][nf], 0, 0, 0); \
    __builtin_amdgcn_s_setprio(0);                                             \
  }

#define WAITBAR(N)                                                             \
    asm volatile("s_waitcnt vmcnt(" #N ")" ::: "memory");                      \
    __builtin_amdgcn_s_barrier();                                              \
    __builtin_amdgcn_sched_barrier(0);

    #pragma unroll 1
    for (int t3 = 0; t3 < 10; ++t3) {
        KSTEP(t3 * 3 + 0, 0, 2) WAITBAR(12)
        KSTEP(t3 * 3 + 1, 1, 0) WAITBAR(12)
        KSTEP(t3 * 3 + 2, 2, 1) WAITBAR(12)
    }
    KSTEP(30, 0, 0)            // issues A(31) only
    WAITBAR(8)                 // B(31) done; A(31) in flight (compiler waits at cvt)
    KSTEP(31, 1, 0)

#undef KSTEP
#undef WAITBAR

    // ---- epilogue: s(row) = sum over this wave's 128 cols of tanh(acc+qb)*w2 ----
    float qv[8], wvv[8];
    #pragma unroll
    for (int nf = 0; nf < 8; ++nf) {
        int c = wn * 128 + nf * 16 + l16;
        qv[nf]  = qb[(size_t)b * H_ + c];
        wvv[nf] = W2[c];
    }
    #pragma unroll
    for (int mf = 0; mf < 4; ++mf) {
        #pragma unroll
        for (int r = 0; r < 4; ++r) {
            float s = 0.0f;
            #pragma unroll
            for (int nf = 0; nf < 8; ++nf) {
                float x = acc[mf][nf][r] + qv[nf];
                float t = 1.0f - 2.0f / (1.0f + __expf(2.0f * x)); // tanh, saturates
                s = fmaf(t, wvv[nf], s);
            }
            s += __shfl_xor(s, 1);
            s += __shfl_xor(s, 2);
            s += __shfl_xor(s, 4);
            s += __shfl_xor(s, 8);
            if (l16 == 0)
                red[(wm * 64 + mf * 16 + quad * 4 + r) * 4 + wn] = s;
        }
    }
    __syncthreads();
    if (tid < 128) {
        int pos = blk * 128 + tid;
        if (pos < cnt) {
            float s = red[tid * 4] + red[tid * 4 + 1] + red[tid * 4 + 2] + red[tid * 4 + 3];
            score[glist[(size_t)b * S_ + pos]] = s;
        }
    }
}

// ---------- Kernel S: + b2, mask, stable softmax per batch row ----------
// masked entries read poisoned score but are replaced by -10000 before use.
__global__ __launch_bounds__(256) void k_softmax(const float* __restrict__ score,
                                                 const float* __restrict__ b2,
                                                 const int*   __restrict__ mask,
                                                 float* __restrict__ p_out) {
    int b = blockIdx.x, tid = threadIdx.x;
    __shared__ float red[256];
    float loc[8];
    float b2v = b2[0];
    float mx = -1e30f;
    #pragma unroll
    for (int i = 0; i < 8; ++i) {
        size_t r = (size_t)b * S_ + i * 256 + tid;
        float v = score[r] + b2v;
        if (mask[r] == 0) v = -10000.0f;
        loc[i] = v;
        mx = fmaxf(mx, v);
    }
    red[tid] = mx; __syncthreads();
    for (int o = 128; o > 0; o >>= 1) {
        if (tid < o) red[tid] = fmaxf(red[tid], red[tid + o]);
        __syncthreads();
    }
    mx = red[0]; __syncthreads();
    float se = 0.0f;
    #pragma unroll
    for (int i = 0; i < 8; ++i) {
        float e = __expf(loc[i] - mx);
        loc[i] = e;
        se += e;
    }
    red[tid] = se; __syncthreads();
    for (int o = 128; o > 0; o >>= 1) {
        if (tid < o) red[tid] += red[tid + o];
        __syncthreads();
    }
    float inv = 1.0f / red[0];
    #pragma unroll
    for (int i = 0; i < 8; ++i)
        p_out[(size_t)b * S_ + i * 256 + tid] = loc[i] * inv;
}

// ---------- Kernel E: partial expected_ctx over 128-entry compacted chunks ----------
// masked rows have p == 0 exactly (exp(-10000-mx) underflows) and are skipped.
__global__ __launch_bounds__(256) void k_expected(const float* __restrict__ ctx,
                                                  const float* __restrict__ p,
                                                  const int*   __restrict__ glist,
                                                  const int*   __restrict__ cnts,
                                                  float* __restrict__ partial) {
    int b = blockIdx.x, ch = blockIdx.y, tid = threadIdx.x;
    const int cnt = cnts[b];
    const int n0 = ch * 128;
    int nloc = cnt - n0;
    if (nloc > 128) nloc = 128;
    __shared__ float ps[128];
    __shared__ int   gi[128];
    if (tid < 128) {
        int g = glist[(size_t)b * S_ + n0 + tid];
        gi[tid] = g;
        ps[tid] = (n0 + tid < cnt) ? p[g] : 0.0f;
    }
    __syncthreads();
    float ax = 0.f, ay = 0.f, az = 0.f, aw = 0.f;
    #pragma unroll 4
    for (int s = 0; s < nloc; ++s) {
        const float4 v = *(const float4*)(ctx + (size_t)gi[s] * DC + tid * 4);
        float w = ps[s];
        ax = fmaf(w, v.x, ax);
        ay = fmaf(w, v.y, ay);
        az = fmaf(w, v.z, az);
        aw = fmaf(w, v.w, aw);
    }
    float4 o = { ax, ay, az, aw };
    *(float4*)(partial + ((size_t)(b * NCH + ch)) * DC + tid * 4) = o;
}

// ---------- Kernel R: reduce chunks -> expected_ctx ----------
__global__ __launch_bounds__(256) void k_reduce(const float* __restrict__ partial,
                                                float* __restrict__ out) {
    int b = blockIdx.x, tid = threadIdx.x;
    float4 acc = { 0.f, 0.f, 0.f, 0.f };
    #pragma unroll
    for (int c = 0; c < NCH; ++c) {
        const float4 v = *(const float4*)(partial + ((size_t)(b * NCH + c)) * DC + tid * 4);
        acc.x += v.x; acc.y += v.y; acc.z += v.z; acc.w += v.w;
    }
    *(float4*)(out + (size_t)b * DC + tid * 4) = acc;
}

extern "C" void kernel_launch(void* const* d_in, const int* in_sizes, int n_in,
                              void* d_out, int out_size, void* d_ws, size_t ws_size,
                              hipStream_t stream) {
    (void)in_sizes; (void)n_in; (void)out_size; (void)ws_size;
    const float* ctx   = (const float*)d_in[0];
    const float* query = (const float*)d_in[1];
    const float* W1    = (const float*)d_in[2];
    const float* b1    = (const float*)d_in[3];
    const float* W2    = (const float*)d_in[4];
    const float* b2    = (const float*)d_in[5];
    const int*   mask  = (const int*)d_in[6];

    float* out      = (float*)d_out;
    float* expected = out;                 // 32*1024
    float* p_out    = out + 32768;         // 32*2048

    char* w = (char*)d_ws;
    bf16*  WcT2      = (bf16*)w;                                    // 1 MB  [kb][h][kk]
    float* qb        = (float*)(w + (1 << 20));                     // 64 KB
    float* score     = (float*)(w + (1 << 20) + (64 << 10));        // 256 KB
    int*   glist     = (int*)  (w + (1 << 20) + (320 << 10));       // 256 KB
    int*   cnts      = (int*)  (w + (1 << 20) + (576 << 10));       // 128 B
    float* partial_e = (float*)(w + (2 << 20));                     // 2 MB

    k_prep    <<<544, 256, 0, stream>>>(W1, query, b1, mask, WcT2, qb, glist, cnts);
    k_gemm    <<<B_ * NBLK, 512, 0, stream>>>(ctx, WcT2, qb, W2, glist, cnts, score);
    k_softmax <<<B_, 256, 0, stream>>>(score, b2, mask, p_out);
    k_expected<<<dim3(B_, NCH), 256, 0, stream>>>(ctx, p_out, glist, cnts, partial_e);
    k_reduce  <<<B_, 256, 0, stream>>>(partial_e, expected);
}

// Round 4
// 461.240 us; speedup vs baseline: 1.2400x; 1.2400x over previous
//
#include <hip/hip_runtime.h>

typedef __bf16 bf16;
typedef __attribute__((ext_vector_type(8))) __bf16 bf16x8;
typedef __attribute__((ext_vector_type(4))) __bf16 bf16x4;
typedef __attribute__((ext_vector_type(4))) float f32x4;

#define B_  32
#define S_  2048
#define DC  1024
#define DQ  1024
#define H_  512
#define BK  32
#define NCH 16             // s-chunks for expected_ctx (compacted: 16 x 128 covers 2048)
#define NBLK 16            // row-blocks per batch in k_gemm (16 x 128 = 2048 worst case)

// async global->LDS, 16B per lane
#define GLD16(g, l) __builtin_amdgcn_global_load_lds( \
    (__attribute__((address_space(1))) void*)(g),     \
    (__attribute__((address_space(3))) void*)(l), 16, 0, 0)

// ---------- Prep ----------
// blocks 0..255   : Wc -> bf16 transpose tiles  WcT2 [kb(32)][h(512)][kk(32)]
// blocks 256..511 : qb[b][h] = query[b] . Wq[:,h] + b1[h]
// blocks 512..543 : per-batch compaction of mask==1 row indices (global row ids)
__global__ __launch_bounds__(256) void k_prep(const float* __restrict__ W1,
                                              const float* __restrict__ query,
                                              const float* __restrict__ b1,
                                              const int*   __restrict__ mask,
                                              bf16* __restrict__ WcT2,
                                              float* __restrict__ qb,
                                              int* __restrict__ glist,
                                              int* __restrict__ cnts) {
    const int bid = blockIdx.x, tid = threadIdx.x;
    if (bid < 256) {
        // W1[:1024] (k-major) -> WcT2 [kb][h][kk] bf16
        __shared__ bf16 t[32 * 68];            // [kk][h-in-tile], pad 4
        const int kb = bid >> 3;               // 0..31
        const int cb = bid & 7;                // 0..7, 64-col tile
        #pragma unroll
        for (int i = 0; i < 2; ++i) {
            int idx = i * 256 + tid;           // 0..511
            int k  = idx >> 4;                 // 0..31
            int h4 = (idx & 15) * 4;           // 0..60
            const float4 v = *(const float4*)(W1 + ((size_t)(kb * 32 + k)) * H_ + cb * 64 + h4);
            bf16x4 pk = { (bf16)v.x, (bf16)v.y, (bf16)v.z, (bf16)v.w };
            *(bf16x4*)(&t[k * 68 + h4]) = pk;
        }
        __syncthreads();
        const int col = tid >> 2;              // 0..63
        const int kk0 = (tid & 3) * 8;         // 0,8,16,24
        bf16x8 o;
        #pragma unroll
        for (int j = 0; j < 8; ++j) o[j] = t[(kk0 + j) * 68 + col];
        *(bf16x8*)(WcT2 + (size_t)kb * 16384 + (size_t)(cb * 64 + col) * 32 + kk0) = o;
    } else if (bid < 512) {
        // qb GEMV
        const int r = bid - 256;
        const int hblk = r & 7;                // 0..7
        const int b    = r >> 3;               // 0..31
        __shared__ float q[DQ];
        __shared__ float red[256];
        #pragma unroll
        for (int i = 0; i < 4; ++i)
            q[tid + i * 256] = query[(size_t)b * DQ + tid + i * 256];
        __syncthreads();
        const int h  = hblk * 64 + (tid & 63);
        const int kc = tid >> 6;               // 0..3
        const float* w = W1 + (size_t)DC * H_ + (size_t)(kc * 256) * H_ + h;
        const float* qv = q + kc * 256;
        float acc = 0.0f;
        #pragma unroll 8
        for (int k = 0; k < 256; ++k)
            acc = fmaf(qv[k], w[(size_t)k * H_], acc);
        red[tid] = acc;
        __syncthreads();
        if (tid < 64)
            qb[(size_t)b * H_ + hblk * 64 + tid] =
                red[tid] + red[tid + 64] + red[tid + 128] + red[tid + 192] + b1[hblk * 64 + tid];
    } else {
        // compaction: list of global row ids (b*2048+s) where mask==1, padded with b*2048
        const int b = bid - 512;
        __shared__ int sc[256];
        int c = 0;
        #pragma unroll
        for (int i = 0; i < 8; ++i)
            if (mask[(size_t)b * S_ + tid * 8 + i] != 0) ++c;
        sc[tid] = c;
        __syncthreads();
        for (int o = 1; o < 256; o <<= 1) {
            int v = sc[tid];
            int u = (tid >= o) ? sc[tid - o] : 0;
            __syncthreads();
            sc[tid] = v + u;
            __syncthreads();
        }
        const int total = sc[255];
        int w = sc[tid] - c;                   // exclusive offset
        for (int i = 0; i < 8; ++i) {
            int s = tid * 8 + i;
            if (mask[(size_t)b * S_ + s] != 0)
                glist[(size_t)b * S_ + (w++)] = b * S_ + s;
        }
        for (int pos = total + tid; pos < S_; pos += 256)
            glist[(size_t)b * S_ + pos] = b * S_;
        if (tid == 0) cnts[b] = total;
    }
}

// ---------- Kernel G: score[row] = sum_h tanh(ctx@Wc + qb)[h]*w2[h], unmasked rows only ----
// ROUND-0 PROVEN STRUCTURE (80 KB LDS -> 2 blocks/CU co-resident; one
// __syncthreads per k-step; B via global_load_lds; A float4->LDS), with the
// only delta being compaction: per-thread A row base gathered via glist,
// epilogue scatter-store, inactive blocks exit. 512 thr = 8 waves (2m x 4n).
__global__ __launch_bounds__(512) void k_gemm(const float* __restrict__ ctx,
                                              const bf16*  __restrict__ WcT2,
                                              const float* __restrict__ qb,
                                              const float* __restrict__ W2,
                                              const int*   __restrict__ glist,
                                              const int*   __restrict__ cnts,
                                              float* __restrict__ score) {
    __shared__ char smem_raw[81920];
    bf16* As = (bf16*)smem_raw;                // [2][128*32]  16 KB
    bf16* Bs = (bf16*)(smem_raw + 16384);      // [2][512*32]  64 KB
    float* red = (float*)smem_raw;             // epilogue reuse of As region

    const int tid = threadIdx.x;
    const int b   = blockIdx.x >> 4;
    const int blk = blockIdx.x & (NBLK - 1);
    const int cnt = cnts[b];
    if (blk * 128 >= cnt) return;

    const int lane = tid & 63;
    const int wave = tid >> 6;
    const int wm   = wave & 1;
    const int wn   = wave >> 1;
    const int l16  = lane & 15;
    const int quad = lane >> 4;

    f32x4 acc[4][8] = {};

    const int am = tid >> 2;                   // 0..127 (compacted tile row)
    const int ak = (tid & 3) << 3;             // 0,8,16,24
    const int grow = glist[(size_t)b * S_ + blk * 128 + am];   // global row id
    const float* actx = ctx + (size_t)grow * DC + ak;
    const int aoff = am * BK + ak;
    const bf16* bsrc = WcT2 + tid * 8;
    const int boff = tid * 8;
    const int fA = (wm * 64 + l16) * BK + quad * 8;
    const int fB = (wn * 128 + l16) * BK + quad * 8;

    // ---- prologue: stage k-step 0 into buffer 0 ----
    {
        const float4 v0 = *(const float4*)(actx);
        const float4 v1 = *(const float4*)(actx + 4);
        bf16x8 a8 = { (bf16)v0.x, (bf16)v0.y, (bf16)v0.z, (bf16)v0.w,
                      (bf16)v1.x, (bf16)v1.y, (bf16)v1.z, (bf16)v1.w };
        *(bf16x8*)(As + aoff) = a8;
        #pragma unroll
        for (int i = 0; i < 4; ++i)
            GLD16(bsrc + i * 4096, Bs + boff + i * 4096);
    }
    __syncthreads();

    for (int kb = 0; kb < DC / BK; ++kb) {
        const int cur = kb & 1, nxt = cur ^ 1;
        float4 av0, av1;
        if (kb < 31) {
            #pragma unroll
            for (int i = 0; i < 4; ++i)
                GLD16(bsrc + (size_t)(kb + 1) * 16384 + i * 4096,
                      Bs + nxt * 16384 + boff + i * 4096);
            av0 = *(const float4*)(actx + (kb + 1) * BK);
            av1 = *(const float4*)(actx + (kb + 1) * BK + 4);
        }

        bf16x8 aF[4], bF[8];
        const bf16* aP = As + cur * 4096 + fA;
        const bf16* bP = Bs + cur * 16384 + fB;
        #pragma unroll
        for (int mf = 0; mf < 4; ++mf) aF[mf] = *(const bf16x8*)(aP + mf * (16 * BK));
        #pragma unroll
        for (int nf = 0; nf < 8; ++nf) bF[nf] = *(const bf16x8*)(bP + nf * (16 * BK));
        #pragma unroll
        for (int mf = 0; mf < 4; ++mf)
            #pragma unroll
            for (int nf = 0; nf < 8; ++nf)
                acc[mf][nf] = __builtin_amdgcn_mfma_f32_16x16x32_bf16(aF[mf], bF[nf], acc[mf][nf], 0, 0, 0);

        if (kb < 31) {
            bf16x8 a8 = { (bf16)av0.x, (bf16)av0.y, (bf16)av0.z, (bf16)av0.w,
                          (bf16)av1.x, (bf16)av1.y, (bf16)av1.z, (bf16)av1.w };
            *(bf16x8*)(As + nxt * 4096 + aoff) = a8;
        }
        __syncthreads();
    }

    // ---- epilogue: s(row) = sum over this wave's 128 cols of tanh(acc+qb)*w2 ----
    float qv[8], wv[8];
    #pragma unroll
    for (int nf = 0; nf < 8; ++nf) {
        int c = wn * 128 + nf * 16 + l16;
        qv[nf] = qb[(size_t)b * H_ + c];
        wv[nf] = W2[c];
    }
    #pragma unroll
    for (int mf = 0; mf < 4; ++mf) {
        #pragma unroll
        for (int r = 0; r < 4; ++r) {
            float s = 0.0f;
            #pragma unroll
            for (int nf = 0; nf < 8; ++nf) {
                float x = acc[mf][nf][r] + qv[nf];
                float t = 1.0f - 2.0f / (1.0f + __expf(2.0f * x)); // tanh, saturates
                s = fmaf(t, wv[nf], s);
            }
            s += __shfl_xor(s, 1);
            s += __shfl_xor(s, 2);
            s += __shfl_xor(s, 4);
            s += __shfl_xor(s, 8);
            if (l16 == 0)
                red[(wm * 64 + mf * 16 + quad * 4 + r) * 4 + wn] = s;
        }
    }
    __syncthreads();
    if (tid < 128) {
        int pos = blk * 128 + tid;
        if (pos < cnt) {
            float s = red[tid * 4] + red[tid * 4 + 1] + red[tid * 4 + 2] + red[tid * 4 + 3];
            score[glist[(size_t)b * S_ + pos]] = s;
        }
    }
}

// ---------- Kernel S: + b2, mask, stable softmax per batch row ----------
// masked entries read poisoned score but are replaced by -10000 before use.
__global__ __launch_bounds__(256) void k_softmax(const float* __restrict__ score,
                                                 const float* __restrict__ b2,
                                                 const int*   __restrict__ mask,
                                                 float* __restrict__ p_out) {
    int b = blockIdx.x, tid = threadIdx.x;
    __shared__ float red[256];
    float loc[8];
    float b2v = b2[0];
    float mx = -1e30f;
    #pragma unroll
    for (int i = 0; i < 8; ++i) {
        size_t r = (size_t)b * S_ + i * 256 + tid;
        float v = score[r] + b2v;
        if (mask[r] == 0) v = -10000.0f;
        loc[i] = v;
        mx = fmaxf(mx, v);
    }
    red[tid] = mx; __syncthreads();
    for (int o = 128; o > 0; o >>= 1) {
        if (tid < o) red[tid] = fmaxf(red[tid], red[tid + o]);
        __syncthreads();
    }
    mx = red[0]; __syncthreads();
    float se = 0.0f;
    #pragma unroll
    for (int i = 0; i < 8; ++i) {
        float e = __expf(loc[i] - mx);
        loc[i] = e;
        se += e;
    }
    red[tid] = se; __syncthreads();
    for (int o = 128; o > 0; o >>= 1) {
        if (tid < o) red[tid] += red[tid + o];
        __syncthreads();
    }
    float inv = 1.0f / red[0];
    #pragma unroll
    for (int i = 0; i < 8; ++i)
        p_out[(size_t)b * S_ + i * 256 + tid] = loc[i] * inv;
}

// ---------- Kernel E: partial expected_ctx over 128-entry compacted chunks ----------
// masked rows have p == 0 exactly (exp(-10000-mx) underflows) and are skipped.
__global__ __launch_bounds__(256) void k_expected(const float* __restrict__ ctx,
                                                  const float* __restrict__ p,
                                                  const int*   __restrict__ glist,
                                                  const int*   __restrict__ cnts,
                                                  float* __restrict__ partial) {
    int b = blockIdx.x, ch = blockIdx.y, tid = threadIdx.x;
    const int cnt = cnts[b];
    const int n0 = ch * 128;
    int nloc = cnt - n0;
    if (nloc > 128) nloc = 128;
    __shared__ float ps[128];
    __shared__ int   gi[128];
    if (tid < 128) {
        int g = glist[(size_t)b * S_ + n0 + tid];
        gi[tid] = g;
        ps[tid] = (n0 + tid < cnt) ? p[g] : 0.0f;
    }
    __syncthreads();
    float ax = 0.f, ay = 0.f, az = 0.f, aw = 0.f;
    #pragma unroll 4
    for (int s = 0; s < nloc; ++s) {
        const float4 v = *(const float4*)(ctx + (size_t)gi[s] * DC + tid * 4);
        float w = ps[s];
        ax = fmaf(w, v.x, ax);
        ay = fmaf(w, v.y, ay);
        az = fmaf(w, v.z, az);
        aw = fmaf(w, v.w, aw);
    }
    float4 o = { ax, ay, az, aw };
    *(float4*)(partial + ((size_t)(b * NCH + ch)) * DC + tid * 4) = o;
}

// ---------- Kernel R: reduce chunks -> expected_ctx ----------
__global__ __launch_bounds__(256) void k_reduce(const float* __restrict__ partial,
                                                float* __restrict__ out) {
    int b = blockIdx.x, tid = threadIdx.x;
    float4 acc = { 0.f, 0.f, 0.f, 0.f };
    #pragma unroll
    for (int c = 0; c < NCH; ++c) {
        const float4 v = *(const float4*)(partial + ((size_t)(b * NCH + c)) * DC + tid * 4);
        acc.x += v.x; acc.y += v.y; acc.z += v.z; acc.w += v.w;
    }
    *(float4*)(out + (size_t)b * DC + tid * 4) = acc;
}

extern "C" void kernel_launch(void* const* d_in, const int* in_sizes, int n_in,
                              void* d_out, int out_size, void* d_ws, size_t ws_size,
                              hipStream_t stream) {
    (void)in_sizes; (void)n_in; (void)out_size; (void)ws_size;
    const float* ctx   = (const float*)d_in[0];
    const float* query = (const float*)d_in[1];
    const float* W1    = (const float*)d_in[2];
    const float* b1    = (const float*)d_in[3];
    const float* W2    = (const float*)d_in[4];
    const float* b2    = (const float*)d_in[5];
    const int*   mask  = (const int*)d_in[6];

    float* out      = (float*)d_out;
    float* expected = out;                 // 32*1024
    float* p_out    = out + 32768;         // 32*2048

    char* w = (char*)d_ws;
    bf16*  WcT2      = (bf16*)w;                                    // 1 MB  [kb][h][kk]
    float* qb        = (float*)(w + (1 << 20));                     // 64 KB
    float* score     = (float*)(w + (1 << 20) + (64 << 10));        // 256 KB
    int*   glist     = (int*)  (w + (1 << 20) + (320 << 10));       // 256 KB
    int*   cnts      = (int*)  (w + (1 << 20) + (576 << 10));       // 128 B
    float* partial_e = (float*)(w + (2 << 20));                     // 2 MB

    k_prep    <<<544, 256, 0, stream>>>(W1, query, b1, mask, WcT2, qb, glist, cnts);
    k_gemm    <<<B_ * NBLK, 512, 0, stream>>>(ctx, WcT2, qb, W2, glist, cnts, score);
    k_softmax <<<B_, 256, 0, stream>>>(score, b2, mask, p_out);
    k_expected<<<dim3(B_, NCH), 256, 0, stream>>>(ctx, p_out, glist, cnts, partial_e);
    k_reduce  <<<B_, 256, 0, stream>>>(partial_e, expected);
}

// Round 5
// 460.189 us; speedup vs baseline: 1.2428x; 1.0023x over previous
//
#include <hip/hip_runtime.h>

typedef __bf16 bf16;
typedef __attribute__((ext_vector_type(8))) __bf16 bf16x8;
typedef __attribute__((ext_vector_type(4))) __bf16 bf16x4;
typedef __attribute__((ext_vector_type(4))) float f32x4;

#define B_  32
#define S_  2048
#define DC  1024
#define DQ  1024
#define H_  512
#define BK  32
#define NCH 16             // s-chunks for expected_ctx (compacted: 16 x 128 covers 2048)
#define NBLK 16            // row-blocks per batch in k_gemm (16 x 128 = 2048 worst case)

// async global->LDS, 16B per lane
#define GLD16(g, l) __builtin_amdgcn_global_load_lds( \
    (__attribute__((address_space(1))) void*)(g),     \
    (__attribute__((address_space(3))) void*)(l), 16, 0, 0)

// ---------- Prep ----------
// blocks 0..255   : Wc -> bf16 transpose tiles  WcT2 [kb(32)][h(512)][kk(32)]
// blocks 256..511 : qb[b][h] = query[b] . Wq[:,h] + b1[h]
// blocks 512..543 : per-batch compaction of mask==1 row indices (global row ids)
__global__ __launch_bounds__(256) void k_prep(const float* __restrict__ W1,
                                              const float* __restrict__ query,
                                              const float* __restrict__ b1,
                                              const int*   __restrict__ mask,
                                              bf16* __restrict__ WcT2,
                                              float* __restrict__ qb,
                                              int* __restrict__ glist,
                                              int* __restrict__ cnts) {
    const int bid = blockIdx.x, tid = threadIdx.x;
    if (bid < 256) {
        // W1[:1024] (k-major) -> WcT2 [kb][h][kk] bf16
        __shared__ bf16 t[32 * 68];            // [kk][h-in-tile], pad 4
        const int kb = bid >> 3;               // 0..31
        const int cb = bid & 7;                // 0..7, 64-col tile
        #pragma unroll
        for (int i = 0; i < 2; ++i) {
            int idx = i * 256 + tid;           // 0..511
            int k  = idx >> 4;                 // 0..31
            int h4 = (idx & 15) * 4;           // 0..60
            const float4 v = *(const float4*)(W1 + ((size_t)(kb * 32 + k)) * H_ + cb * 64 + h4);
            bf16x4 pk = { (bf16)v.x, (bf16)v.y, (bf16)v.z, (bf16)v.w };
            *(bf16x4*)(&t[k * 68 + h4]) = pk;
        }
        __syncthreads();
        const int col = tid >> 2;              // 0..63
        const int kk0 = (tid & 3) * 8;         // 0,8,16,24
        bf16x8 o;
        #pragma unroll
        for (int j = 0; j < 8; ++j) o[j] = t[(kk0 + j) * 68 + col];
        *(bf16x8*)(WcT2 + (size_t)kb * 16384 + (size_t)(cb * 64 + col) * 32 + kk0) = o;
    } else if (bid < 512) {
        // qb GEMV
        const int r = bid - 256;
        const int hblk = r & 7;                // 0..7
        const int b    = r >> 3;               // 0..31
        __shared__ float q[DQ];
        __shared__ float red[256];
        #pragma unroll
        for (int i = 0; i < 4; ++i)
            q[tid + i * 256] = query[(size_t)b * DQ + tid + i * 256];
        __syncthreads();
        const int h  = hblk * 64 + (tid & 63);
        const int kc = tid >> 6;               // 0..3
        const float* w = W1 + (size_t)DC * H_ + (size_t)(kc * 256) * H_ + h;
        const float* qv = q + kc * 256;
        float acc = 0.0f;
        #pragma unroll 8
        for (int k = 0; k < 256; ++k)
            acc = fmaf(qv[k], w[(size_t)k * H_], acc);
        red[tid] = acc;
        __syncthreads();
        if (tid < 64)
            qb[(size_t)b * H_ + hblk * 64 + tid] =
                red[tid] + red[tid + 64] + red[tid + 128] + red[tid + 192] + b1[hblk * 64 + tid];
    } else {
        // compaction: list of global row ids (b*2048+s) where mask==1, padded with b*2048
        const int b = bid - 512;
        __shared__ int sc[256];
        int c = 0;
        #pragma unroll
        for (int i = 0; i < 8; ++i)
            if (mask[(size_t)b * S_ + tid * 8 + i] != 0) ++c;
        sc[tid] = c;
        __syncthreads();
        for (int o = 1; o < 256; o <<= 1) {
            int v = sc[tid];
            int u = (tid >= o) ? sc[tid - o] : 0;
            __syncthreads();
            sc[tid] = v + u;
            __syncthreads();
        }
        const int total = sc[255];
        int w = sc[tid] - c;                   // exclusive offset
        for (int i = 0; i < 8; ++i) {
            int s = tid * 8 + i;
            if (mask[(size_t)b * S_ + s] != 0)
                glist[(size_t)b * S_ + (w++)] = b * S_ + s;
        }
        for (int pos = total + tid; pos < S_; pos += 256)
            glist[(size_t)b * S_ + pos] = b * S_;
        if (tid == 0) cnts[b] = total;
    }
}

// ---------- Kernel G: partial score over one H-half, unmasked rows only ----------
// Round-0 proven loop structure, BN=256 (H split across twin blocks h2=0/1):
// LDS 48 KB -> 3 blocks/CU capacity; ~2x active blocks -> co-resident overlap
// restored. Twin blocks (consecutive blockIdx) read the same A rows -> L3 hit.
// scorep[h2][row] partials; k_softmax sums both halves.
// 512 thr = 8 waves (2m x 4n), wave tile 64x64, acc[4][4].
__global__ __launch_bounds__(512) void k_gemm(const float* __restrict__ ctx,
                                              const bf16*  __restrict__ WcT2,
                                              const float* __restrict__ qb,
                                              const float* __restrict__ W2,
                                              const int*   __restrict__ glist,
                                              const int*   __restrict__ cnts,
                                              float* __restrict__ scorep) {
    __shared__ char smem_raw[49152];
    bf16* As = (bf16*)smem_raw;                // [2][128*32]  16 KB
    bf16* Bs = (bf16*)(smem_raw + 16384);      // [2][256*32]  32 KB
    float* red = (float*)smem_raw;             // epilogue reuse of As region

    const int tid = threadIdx.x;
    const int h2  = blockIdx.x & 1;
    const int blk = (blockIdx.x >> 1) & (NBLK - 1);
    const int b   = blockIdx.x >> 5;
    const int cnt = cnts[b];
    if (blk * 128 >= cnt) return;

    const int lane = tid & 63;
    const int wave = tid >> 6;
    const int wm   = wave & 1;
    const int wn   = wave >> 1;                // 0..3 (64-col n-waves)
    const int l16  = lane & 15;
    const int quad = lane >> 4;

    f32x4 acc[4][4] = {};

    const int am = tid >> 2;                   // 0..127 (compacted tile row)
    const int ak = (tid & 3) << 3;             // 0,8,16,24
    const int grow = glist[(size_t)b * S_ + blk * 128 + am];   // global row id
    const float* actx = ctx + (size_t)grow * DC + ak;
    const int aoff = am * BK + ak;
    const bf16* bsrc = WcT2 + (size_t)h2 * 8192 + tid * 8;     // half-panel source
    const int boff = tid * 8;
    const int fA = (wm * 64 + l16) * BK + quad * 8;
    const int fB = (wn * 64 + l16) * BK + quad * 8;

    // ---- prologue: stage k-step 0 into buffer 0 ----
    {
        const float4 v0 = *(const float4*)(actx);
        const float4 v1 = *(const float4*)(actx + 4);
        bf16x8 a8 = { (bf16)v0.x, (bf16)v0.y, (bf16)v0.z, (bf16)v0.w,
                      (bf16)v1.x, (bf16)v1.y, (bf16)v1.z, (bf16)v1.w };
        *(bf16x8*)(As + aoff) = a8;
        #pragma unroll
        for (int i = 0; i < 2; ++i)
            GLD16(bsrc + i * 4096, Bs + boff + i * 4096);
    }
    __syncthreads();

    for (int kb = 0; kb < DC / BK; ++kb) {
        const int cur = kb & 1, nxt = cur ^ 1;
        float4 av0, av1;
        if (kb < 31) {
            #pragma unroll
            for (int i = 0; i < 2; ++i)
                GLD16(bsrc + (size_t)(kb + 1) * 16384 + i * 4096,
                      Bs + nxt * 8192 + boff + i * 4096);
            av0 = *(const float4*)(actx + (kb + 1) * BK);
            av1 = *(const float4*)(actx + (kb + 1) * BK + 4);
        }

        bf16x8 aF[4], bF[4];
        const bf16* aP = As + cur * 4096 + fA;
        const bf16* bP = Bs + cur * 8192 + fB;
        #pragma unroll
        for (int mf = 0; mf < 4; ++mf) aF[mf] = *(const bf16x8*)(aP + mf * (16 * BK));
        #pragma unroll
        for (int nf = 0; nf < 4; ++nf) bF[nf] = *(const bf16x8*)(bP + nf * (16 * BK));
        #pragma unroll
        for (int mf = 0; mf < 4; ++mf)
            #pragma unroll
            for (int nf = 0; nf < 4; ++nf)
                acc[mf][nf] = __builtin_amdgcn_mfma_f32_16x16x32_bf16(aF[mf], bF[nf], acc[mf][nf], 0, 0, 0);

        if (kb < 31) {
            bf16x8 a8 = { (bf16)av0.x, (bf16)av0.y, (bf16)av0.z, (bf16)av0.w,
                          (bf16)av1.x, (bf16)av1.y, (bf16)av1.z, (bf16)av1.w };
            *(bf16x8*)(As + nxt * 4096 + aoff) = a8;
        }
        __syncthreads();
    }

    // ---- epilogue: partial s(row) over this block's 256 cols ----
    float qv[4], wv[4];
    #pragma unroll
    for (int nf = 0; nf < 4; ++nf) {
        int c = h2 * 256 + wn * 64 + nf * 16 + l16;
        qv[nf] = qb[(size_t)b * H_ + c];
        wv[nf] = W2[c];
    }
    #pragma unroll
    for (int mf = 0; mf < 4; ++mf) {
        #pragma unroll
        for (int r = 0; r < 4; ++r) {
            float s = 0.0f;
            #pragma unroll
            for (int nf = 0; nf < 4; ++nf) {
                float x = acc[mf][nf][r] + qv[nf];
                float t = 1.0f - 2.0f / (1.0f + __expf(2.0f * x)); // tanh, saturates
                s = fmaf(t, wv[nf], s);
            }
            s += __shfl_xor(s, 1);
            s += __shfl_xor(s, 2);
            s += __shfl_xor(s, 4);
            s += __shfl_xor(s, 8);
            if (l16 == 0)
                red[(wm * 64 + mf * 16 + quad * 4 + r) * 4 + wn] = s;
        }
    }
    __syncthreads();
    if (tid < 128) {
        int pos = blk * 128 + tid;
        if (pos < cnt) {
            float s = red[tid * 4] + red[tid * 4 + 1] + red[tid * 4 + 2] + red[tid * 4 + 3];
            scorep[(size_t)h2 * (B_ * S_) + glist[(size_t)b * S_ + pos]] = s;
        }
    }
}

// ---------- Kernel S: sum halves, + b2, mask, stable softmax per batch row ----------
// masked entries read poisoned partials but are replaced by -10000 before use.
__global__ __launch_bounds__(256) void k_softmax(const float* __restrict__ scorep,
                                                 const float* __restrict__ b2,
                                                 const int*   __restrict__ mask,
                                                 float* __restrict__ p_out) {
    int b = blockIdx.x, tid = threadIdx.x;
    __shared__ float red[256];
    float loc[8];
    float b2v = b2[0];
    float mx = -1e30f;
    #pragma unroll
    for (int i = 0; i < 8; ++i) {
        size_t r = (size_t)b * S_ + i * 256 + tid;
        float v = scorep[r] + scorep[(size_t)(B_ * S_) + r] + b2v;
        if (mask[r] == 0) v = -10000.0f;
        loc[i] = v;
        mx = fmaxf(mx, v);
    }
    red[tid] = mx; __syncthreads();
    for (int o = 128; o > 0; o >>= 1) {
        if (tid < o) red[tid] = fmaxf(red[tid], red[tid + o]);
        __syncthreads();
    }
    mx = red[0]; __syncthreads();
    float se = 0.0f;
    #pragma unroll
    for (int i = 0; i < 8; ++i) {
        float e = __expf(loc[i] - mx);
        loc[i] = e;
        se += e;
    }
    red[tid] = se; __syncthreads();
    for (int o = 128; o > 0; o >>= 1) {
        if (tid < o) red[tid] += red[tid + o];
        __syncthreads();
    }
    float inv = 1.0f / red[0];
    #pragma unroll
    for (int i = 0; i < 8; ++i)
        p_out[(size_t)b * S_ + i * 256 + tid] = loc[i] * inv;
}

// ---------- Kernel E: partial expected_ctx over 128-entry compacted chunks ----------
// masked rows have p == 0 exactly (exp(-10000-mx) underflows) and are skipped.
__global__ __launch_bounds__(256) void k_expected(const float* __restrict__ ctx,
                                                  const float* __restrict__ p,
                                                  const int*   __restrict__ glist,
                                                  const int*   __restrict__ cnts,
                                                  float* __restrict__ partial) {
    int b = blockIdx.x, ch = blockIdx.y, tid = threadIdx.x;
    const int cnt = cnts[b];
    const int n0 = ch * 128;
    int nloc = cnt - n0;
    if (nloc > 128) nloc = 128;
    __shared__ float ps[128];
    __shared__ int   gi[128];
    if (tid < 128) {
        int g = glist[(size_t)b * S_ + n0 + tid];
        gi[tid] = g;
        ps[tid] = (n0 + tid < cnt) ? p[g] : 0.0f;
    }
    __syncthreads();
    float ax = 0.f, ay = 0.f, az = 0.f, aw = 0.f;
    #pragma unroll 4
    for (int s = 0; s < nloc; ++s) {
        const float4 v = *(const float4*)(ctx + (size_t)gi[s] * DC + tid * 4);
        float w = ps[s];
        ax = fmaf(w, v.x, ax);
        ay = fmaf(w, v.y, ay);
        az = fmaf(w, v.z, az);
        aw = fmaf(w, v.w, aw);
    }
    float4 o = { ax, ay, az, aw };
    *(float4*)(partial + ((size_t)(b * NCH + ch)) * DC + tid * 4) = o;
}

// ---------- Kernel R: reduce chunks -> expected_ctx ----------
__global__ __launch_bounds__(256) void k_reduce(const float* __restrict__ partial,
                                                float* __restrict__ out) {
    int b = blockIdx.x, tid = threadIdx.x;
    float4 acc = { 0.f, 0.f, 0.f, 0.f };
    #pragma unroll
    for (int c = 0; c < NCH; ++c) {
        const float4 v = *(const float4*)(partial + ((size_t)(b * NCH + c)) * DC + tid * 4);
        acc.x += v.x; acc.y += v.y; acc.z += v.z; acc.w += v.w;
    }
    *(float4*)(out + (size_t)b * DC + tid * 4) = acc;
}

extern "C" void kernel_launch(void* const* d_in, const int* in_sizes, int n_in,
                              void* d_out, int out_size, void* d_ws, size_t ws_size,
                              hipStream_t stream) {
    (void)in_sizes; (void)n_in; (void)out_size; (void)ws_size;
    const float* ctx   = (const float*)d_in[0];
    const float* query = (const float*)d_in[1];
    const float* W1    = (const float*)d_in[2];
    const float* b1    = (const float*)d_in[3];
    const float* W2    = (const float*)d_in[4];
    const float* b2    = (const float*)d_in[5];
    const int*   mask  = (const int*)d_in[6];

    float* out      = (float*)d_out;
    float* expected = out;                 // 32*1024
    float* p_out    = out + 32768;         // 32*2048

    char* w = (char*)d_ws;
    bf16*  WcT2      = (bf16*)w;                                    // 1 MB  [kb][h][kk]
    float* qb        = (float*)(w + (1 << 20));                     // 64 KB
    float* scorep    = (float*)(w + (1 << 20) + (64 << 10));        // 512 KB (two halves)
    int*   glist     = (int*)  (w + (1 << 20) + (576 << 10));       // 256 KB
    int*   cnts      = (int*)  (w + (1 << 20) + (832 << 10));       // 128 B
    float* partial_e = (float*)(w + (2 << 20));                     // 2 MB

    k_prep    <<<544, 256, 0, stream>>>(W1, query, b1, mask, WcT2, qb, glist, cnts);
    k_gemm    <<<B_ * NBLK * 2, 512, 0, stream>>>(ctx, WcT2, qb, W2, glist, cnts, scorep);
    k_softmax <<<B_, 256, 0, stream>>>(scorep, b2, mask, p_out);
    k_expected<<<dim3(B_, NCH), 256, 0, stream>>>(ctx, p_out, glist, cnts, partial_e);
    k_reduce  <<<B_, 256, 0, stream>>>(partial_e, expected);
}